// Round 3
// baseline (1254.104 us; speedup 1.0000x reference)
//
#include <hip/hip_runtime.h>
#include <hip/hip_bf16.h>
#include <stdint.h>

#define NIMG 8
#define NCLS 21
#define HW   4096
#define CF   768
#define NK   2
#define NJ   42
#define NJP  48
#define SINK_MAX 100

using uint32 = unsigned int;
using u16    = unsigned short;

__device__ __forceinline__ float b2f(u16 u){ union{uint32 i; float f;} x; x.i=((uint32)u)<<16; return x.f; }
__device__ __forceinline__ u16 f2b(float f){ union{float f; uint32 i;} x; x.f=f; return (u16)((x.i + 0x7fffu + ((x.i>>16)&1u))>>16); }

template<int BF>
__device__ __forceinline__ float ldin(const void* p, size_t idx){
    if (BF) return b2f(((const u16*)p)[idx]);
    return ((const float*)p)[idx];
}
template<int BF>
__device__ __forceinline__ void stout(void* p, size_t idx, float v){
    if (BF) ((u16*)p)[idx] = f2b(v);
    else    ((float*)p)[idx] = v;
}

// xor-swizzle within 32-lane halves (offs <=8 stay inside each 16-lane group)
template<int IMM>
__device__ __forceinline__ double swz_add_f64(double v){
    union{ double d; unsigned int u[2]; } x, y;
    x.d = v;
    y.u[0] = __builtin_amdgcn_ds_swizzle(x.u[0], IMM);
    y.u[1] = __builtin_amdgcn_ds_swizzle(x.u[1], IMM);
    return v + y.d;
}

// ---------------- 0. dtype detect: bf16 (flag=1) vs f32 (flag=0) -------------
__global__ void k_detect(const void* feat, int* flag){
    __shared__ int cnt;
    if (threadIdx.x == 0) cnt = 0;
    __syncthreads();
    const u16* f = (const u16*)feat;
    int bad = 0;
    for (int i = threadIdx.x; i < 4096; i += 256){
        int ex = (f[i] >> 7) & 0xFF;        // bf16 exponent field
        if (ex >= 160) bad++;               // |v| >= 2^33: impossible for N(0,1) bf16
    }
    atomicAdd(&cnt, bad);
    __syncthreads();
    if (threadIdx.x == 0) *flag = (cnt < 64) ? 1 : 0;
}

// ---------------- 1. per-pixel class assignment (argmax CAM, label-gated) ----
template<int BF>
__global__ void k_seeds(const void* __restrict__ cam, const void* __restrict__ label,
                        int* __restrict__ pix_cls, const int* __restrict__ dflag){
    if (*dflag != BF) return;
    int g = blockIdx.x*256 + threadIdx.x;        // NIMG*HW threads
    int n = g >> 12, p = g & 4095;
    float best = -1e30f; int bel = 0;
    for (int c = 0; c < NCLS; c++){
        float v = ldin<BF>(cam, (size_t)(n*NCLS + c)*HW + p);
        if (v > best){ best = v; bel = c; }      // strict > : first-max tie-break
    }
    pix_cls[g] = (ldin<BF>(label, n*NCLS + bel) > 0.f) ? bel : -1;
}

// ---------------- 2. per-pixel feature norms (f64 accumulate) ----------------
template<int BF>
__global__ void k_norms(const void* __restrict__ feat, float* __restrict__ inv_n,
                        float* __restrict__ inv_ot, const int* __restrict__ dflag){
    if (*dflag != BF) return;
    int g = blockIdx.x*256 + threadIdx.x;        // NIMG*HW threads
    int n = g >> 12, p = g & 4095;
    double s = 0.0;
    for (int k = 0; k < CF; k++){
        double v = (double)ldin<BF>(feat, (size_t)(n*CF + k)*HW + p);
        s += v*v;
    }
    double nr = sqrt(s);
    inv_n [g] = (float)(1.0/fmax(nr, 1e-8));
    inv_ot[g] = (float)(1.0/(nr + 1e-5));
}

// ------- 3. transpose feature [cf,hw] -> featT [hw,cf] in FULL f32 -----------
// (round-3 post-mortem: bf16-rounding features here was the stable 0.08 error)
template<int BF>
__global__ void k_transpose(const void* __restrict__ feat, float* __restrict__ featT,
                            const int* __restrict__ dflag){
    if (*dflag != BF) return;
    __shared__ float tile[64][65];
    int b = blockIdx.x;
    int n   = b / ((CF/64)*(HW/64));
    int rem = b % ((CF/64)*(HW/64));
    int kb = (rem / (HW/64)) * 64;
    int pb = (rem % (HW/64)) * 64;
    int tx = threadIdx.x & 63, ty = threadIdx.x >> 6;
    for (int i = 0; i < 16; i++){
        int k = ty*16 + i;
        tile[tx][k] = ldin<BF>(feat, ((size_t)(n*CF + kb + k))*HW + pb + tx);
    }
    __syncthreads();
    for (int i = 0; i < 16; i++){
        int p = ty*16 + i;
        featT[((size_t)(n*HW + pb + p))*CF + kb + tx] = tile[p][tx];
    }
}

// ---------------- 4. per-(n,c): count, ordered pixel list, init centers ------
__global__ void k_scan(const int* __restrict__ pix_cls, const float* __restrict__ featT,
                       int* __restrict__ cnt, int* __restrict__ plist,
                       double* __restrict__ centers){
    int b = blockIdx.x; int n = b / NCLS, c = b % NCLS;
    int lane = threadIdx.x;                       // 64 threads = 1 wave
    int* lst = plist + (size_t)b*HW;
    int count = 0, i0 = -1, i1 = -1;
    for (int base = 0; base < HW; base += 64){
        int cls = pix_cls[n*HW + base + lane];
        unsigned long long m = __ballot(cls == c);
        int pos = count + __popcll(m & ((1ull<<lane) - 1ull));
        if (cls == c) lst[pos] = base + lane;
        if (i0 < 0){
            if (m){ i0 = base + __ffsll((long long)m) - 1;
                    unsigned long long m2 = m & (m-1);
                    if (m2) i1 = base + __ffsll((long long)m2) - 1; }
        } else if (i1 < 0){
            if (m) i1 = base + __ffsll((long long)m) - 1;
        }
        count += __popcll(m);
    }
    if (lane == 0) cnt[b] = count;
    double* C0 = centers + (size_t)b*NK*CF;
    if (count >= 2){
        const float* r0 = featT + (size_t)(n*HW + i0)*CF;
        const float* r1 = featT + (size_t)(n*HW + i1)*CF;
        for (int e = lane; e < CF; e += 64){ C0[e] = (double)r0[e]; C0[CF+e] = (double)r1[e]; }
    } else {
        for (int e = lane; e < CF; e += 64){ C0[e] = 0.0; C0[CF+e] = 0.0; }
    }
}

// -------- 5. k-means (<=10 Lloyd iterations) per (n,c) -----------------------
// round-10 theory: per-block-iteration is ~34us regardless of GPU load; the
// cost is the f64 __shfl_xor butterfly paying full LDS latency per WORD
// (bpermute;waitcnt;add x96 per batch). Restructure: 16-lane groups own one
// pixel each; lane owns a 48-elem slice {4s+64t+u}; butterfly = 4 levels of
// single-instruction ds_swizzle (16 words/batch vs 96 bpermutes). Centers
// broadcast from bank-padded Cs2[2][16][49]. Cluster-1 sums derived from the
// precomputed total St (C1 = St - C0; exact pixel partition). Dots stay f64.
// Early-exit and pixel->batch mapping unchanged.
__global__ __launch_bounds__(512, 2) void k_kmeans(const int* __restrict__ cnt,
                                                   const int* __restrict__ plist,
                                                   const float* __restrict__ featT,
                                                   double* __restrict__ centers){
    int b = blockIdx.x; int n = b / NCLS;
    int m = cnt[b];
    if (m < 2) return;                            // centers stay zero (k_scan wrote them)
    __shared__ double Cs[2][CF];                  // 12 KB canonical centers
    __shared__ double Cs2[2][16][49];             // 12.5 KB bank-padded per-sublane rows
    __shared__ float  As[CF];                     // 3 KB cluster-0 sums
    __shared__ float  St[CF];                     // 3 KB total sums (loop-invariant)
    __shared__ double red[2];
    __shared__ float  ck0;
    __shared__ double invn[2];
    __shared__ unsigned char asg[HW];             // 4 KB previous assignment
    __shared__ int    lst_s[HW];                  // 16 KB pixel list
    __shared__ int chg;
    int tid = threadIdx.x, lane = tid & 63, w = tid >> 6;   // w in [0,8)
    int sl = lane & 15;                            // sublane in 16-group
    int g  = lane >> 4;                            // group 0..3 (one pixel each)
    const int* lst = plist + (size_t)b*HW;
    double* Cg = centers + (size_t)b*NK*CF;
    for (int j = tid; j < CF; j += 512){ Cs[0][j] = Cg[j]; Cs[1][j] = Cg[CF+j]; St[j] = 0.f; }
    for (int i = tid; i < m; i += 512){ asg[i] = 255; lst_s[i] = lst[i]; }
    __syncthreads();

    // ---- pre-pass: St[e] = sum over ALL m pixels of feat (lane-sliced) ----
    {
        float a0[48];
        #pragma unroll
        for (int j = 0; j < 48; j++) a0[j] = 0.f;
        for (int i = w; i < m; i += 32){
            int idx = i + 8*g;
            if (idx < m){
                const float* row = featT + (size_t)(n*HW + lst_s[idx])*CF + 4*sl;
                float vv[48];
                #pragma unroll
                for (int t = 0; t < 12; t++) *(float4*)&vv[t*4] = *(const float4*)(row + t*64);
                #pragma unroll
                for (int j = 0; j < 48; j++) a0[j] += vv[j];
            }
        }
        #pragma unroll
        for (int j = 0; j < 48; j++){
            int e = 4*sl + 64*(j>>2) + (j&3);
            atomicAdd(&St[e], a0[j]);
        }
    }
    __syncthreads();

    for (int it = 0; it < 10; it++){
        if (tid < 2) red[tid] = 0.0;
        if (tid == 0){ ck0 = 0.f; chg = 0; }
        __syncthreads();
        double q0 = 0.0, q1 = 0.0;
        for (int j = tid; j < CF; j += 512){ q0 += Cs[0][j]*Cs[0][j]; q1 += Cs[1][j]*Cs[1][j]; }
        #pragma unroll
        for (int off = 32; off; off >>= 1){ q0 += __shfl_xor(q0, off); q1 += __shfl_xor(q1, off); }
        if (lane == 0){ atomicAdd(&red[0], q0); atomicAdd(&red[1], q1); }
        for (int j = tid; j < CF; j += 512) As[j] = 0.f;
        // rearrange centers for conflict-free broadcast reads: Cs2[c][s][4t+u]
        for (int e = tid; e < CF; e += 512){
            int u = e & 3, s = (e >> 2) & 15, t = e >> 6;
            Cs2[0][s][t*4 + u] = Cs[0][e];
            Cs2[1][s][t*4 + u] = Cs[1][e];
        }
        __syncthreads();
        if (tid == 0){
            invn[0] = 1.0/fmax(sqrt(red[0]), 1e-8);
            invn[1] = 1.0/fmax(sqrt(red[1]), 1e-8);
        }
        __syncthreads();
        double ic0 = invn[0], ic1 = invn[1];
        const double* c0row = Cs2[0][sl];
        const double* c1row = Cs2[1][sl];
        float a0[48];
        #pragma unroll
        for (int j = 0; j < 48; j++) a0[j] = 0.f;
        int c0n = 0, c1n = 0, myChg = 0;
        // double-buffered batches: per batch each 16-lane group owns pixel i+8g
        float vA[48], vB[48];
        if (w < m){
            int idx = w + 8*g; int iv = (idx < m) ? idx : (m-1);
            const float* row = featT + (size_t)(n*HW + lst_s[iv])*CF + 4*sl;
            #pragma unroll
            for (int t = 0; t < 12; t++) *(float4*)&vA[t*4] = *(const float4*)(row + t*64);
        }
        if (w + 32 < m){
            int idx = w + 32 + 8*g; int iv = (idx < m) ? idx : (m-1);
            const float* row = featT + (size_t)(n*HW + lst_s[iv])*CF + 4*sl;
            #pragma unroll
            for (int t = 0; t < 12; t++) *(float4*)&vB[t*4] = *(const float4*)(row + t*64);
        }
        for (int i = w; i < m; i += 32){
            // per-lane partial dot over the 48-elem slice (4 chains for ILP)
            double s0a = 0.0, s0b = 0.0, s1a = 0.0, s1b = 0.0;
            #pragma unroll
            for (int j = 0; j < 24; j++){
                double fv = (double)vA[j];
                s0a += fv * c0row[j];
                s1a += fv * c1row[j];
            }
            #pragma unroll
            for (int j = 24; j < 48; j++){
                double fv = (double)vA[j];
                s0b += fv * c0row[j];
                s1b += fv * c1row[j];
            }
            double d0 = s0a + s0b, d1 = s1a + s1b;
            // 4-level swizzle butterfly within the 16-lane group
            d0 = swz_add_f64<0x201F>(d0); d1 = swz_add_f64<0x201F>(d1);   // xor 8
            d0 = swz_add_f64<0x101F>(d0); d1 = swz_add_f64<0x101F>(d1);   // xor 4
            d0 = swz_add_f64<0x081F>(d0); d1 = swz_add_f64<0x081F>(d1);   // xor 2
            d0 = swz_add_f64<0x041F>(d0); d1 = swz_add_f64<0x041F>(d1);   // xor 1
            int idx = i + 8*g;
            if (idx < m){
                int a = (d0*ic0 >= d1*ic1) ? 0 : 1;   // argmax, first-max on tie
                if (sl == 0){
                    if (asg[idx] != (unsigned char)a){ myChg++; asg[idx] = (unsigned char)a; }
                    if (a == 0) c0n++; else c1n++;
                }
                if (a == 0){
                    #pragma unroll
                    for (int j = 0; j < 48; j++) a0[j] += vA[j];
                }
            }
            #pragma unroll
            for (int j = 0; j < 48; j++) vA[j] = vB[j];
            int inext = i + 64;                   // refill B two batches out
            if (inext < m){
                int idx2 = inext + 8*g; int iv2 = (idx2 < m) ? idx2 : (m-1);
                const float* row = featT + (size_t)(n*HW + lst_s[iv2])*CF + 4*sl;
                #pragma unroll
                for (int t = 0; t < 12; t++) *(float4*)&vB[t*4] = *(const float4*)(row + t*64);
            }
        }
        #pragma unroll
        for (int j = 0; j < 48; j++){
            int e = 4*sl + 64*(j>>2) + (j&3);
            atomicAdd(&As[e], a0[j]);
        }
        if (sl == 0){
            atomicAdd(&ck0, (float)c0n);
            if (myChg) atomicAdd(&chg, myChg);
        }
        (void)c1n;
        __syncthreads();
        if (chg == 0) break;                      // exact fixed point: Cs already final
        double dv0 = fmax((double)ck0, 1.0);
        double dv1 = fmax((double)((float)m - ck0), 1.0);
        for (int j = tid; j < CF; j += 512){
            float A0 = As[j];
            Cs[0][j] = (double)A0/dv0;
            Cs[1][j] = (double)(St[j] - A0)/dv1;
        }
        __syncthreads();
    }
    for (int j = tid; j < CF; j += 512){ Cg[j] = Cs[0][j]; Cg[CF+j] = Cs[1][j]; }
}

// ---------------- 6. inverse center norms (f64, both epsilon variants) -------
__global__ void k_invc(const double* __restrict__ centers, float* __restrict__ invc_cam,
                       float* __restrict__ invc_ot){
    int b = blockIdx.x;                           // NIMG*NJ blocks, 64 threads
    int lane = threadIdx.x;
    const double* C = centers + (size_t)b*CF;
    double s = 0.0;
    for (int e = lane; e < CF; e += 64) s += C[e]*C[e];
    for (int off = 32; off; off >>= 1) s += __shfl_xor(s, off);
    if (lane == 0){
        double nr = sqrt(s);
        invc_cam[b] = (float)(1.0/fmax(nr, 1e-8));
        invc_ot[b]  = (float)(1.0/(nr + 1e-5));
    }
}

// ---------------- 7. centers f64 -> f32 padded [48,768] ----------------------
__global__ void k_cf32(const double* __restrict__ centers, float* __restrict__ Cf32){
    int n = blockIdx.x; int tid = threadIdx.x;
    for (int idx = tid; idx < NJP*CF; idx += 256){
        int j = idx / CF, e = idx - j*CF;
        float v = (j < NJ) ? (float)centers[((size_t)n*NJ + j)*CF + e] : 0.f;
        Cf32[(size_t)n*NJP*CF + idx] = v;
    }
}

// ---------------- 8. big sim GEMM in f32: D[p][j] = feat[p]·C[j] -------------
__global__ __launch_bounds__(256) void k_gemmf(const float* __restrict__ featT,
                                               const float* __restrict__ Cf32,
                                               float* __restrict__ D){
    __shared__ float Fs[128][66];                 // [k][p], padded
    int b = blockIdx.x; int n = b >> 6; int pbase = (b & 63)*64;
    int tid = threadIdx.x, p = tid & 63;
    int jb = __builtin_amdgcn_readfirstlane((tid >> 6)*12);   // wave-uniform j-base
    float acc[12];
    #pragma unroll
    for (int j = 0; j < 12; j++) acc[j] = 0.f;
    for (int kc = 0; kc < CF; kc += 128){
        __syncthreads();
        for (int idx = tid; idx < 64*64; idx += 256){         // 64 px × 64 float2
            int pp = idx >> 6, cw = idx & 63;
            float2 wv = *(const float2*)(featT + (size_t)(n*HW + pbase + pp)*CF + kc + cw*2);
            Fs[cw*2    ][pp] = wv.x;
            Fs[cw*2 + 1][pp] = wv.y;
        }
        __syncthreads();
        const float* Cb = Cf32 + (size_t)n*NJP*CF + kc;
        for (int k8 = 0; k8 < 128; k8 += 8){
            #pragma unroll
            for (int j = 0; j < 12; j++){
                const float* cr = Cb + (size_t)(jb + j)*CF + k8;
                #pragma unroll
                for (int k = 0; k < 8; k++)
                    acc[j] += Fs[k8 + k][p] * cr[k];
            }
        }
    }
    float* dp = D + ((size_t)(n*HW + pbase + p))*NJP + jb;
    #pragma unroll
    for (int j = 0; j < 12; j++) dp[j] = acc[j];
}

// ---------------- 9. output 0: cam, max-normalized ---------------------------
template<int BF>
__global__ __launch_bounds__(256) void k_out0(const float* __restrict__ D,
                                              const float* __restrict__ inv_n,
                                              const float* __restrict__ invc_cam,
                                              const int* __restrict__ cnt,
                                              void* __restrict__ out0,
                                              const int* __restrict__ dflag){
    if (*dflag != BF) return;
    int b = blockIdx.x; int n = b / NCLS, c = b % NCLS;
    __shared__ float wmax[4]; __shared__ float sden;
    int tid = threadIdx.x, lane = tid & 63, w = tid >> 6;
    size_t obase = (size_t)b*HW;
    if (cnt[b] < 2){
        for (int p = tid; p < HW; p += 256) stout<BF>(out0, obase + p, 0.f);
        return;
    }
    float ic0 = invc_cam[n*NJ + 2*c], ic1 = invc_cam[n*NJ + 2*c + 1];
    const float* Dn = D + (size_t)n*HW*NJP;
    float mx = -1e30f;
    for (int p = tid; p < HW; p += 256){
        const float* dp = Dn + (size_t)p*NJP + 2*c;
        float camv = 0.5f*(dp[0]*ic0 + dp[1]*ic1)*inv_n[n*HW + p];
        mx = fmaxf(mx, camv);
    }
    for (int off = 32; off; off >>= 1) mx = fmaxf(mx, __shfl_xor(mx, off));
    if (lane == 0) wmax[w] = mx;
    __syncthreads();
    if (tid == 0) sden = fmaxf(fmaxf(wmax[0], wmax[1]), fmaxf(wmax[2], wmax[3])) + 1e-5f;
    __syncthreads();
    float den = sden;
    for (int p = tid; p < HW; p += 256){
        const float* dp = Dn + (size_t)p*NJP + 2*c;
        float camv = 0.5f*(dp[0]*ic0 + dp[1]*ic1)*inv_n[n*HW + p];
        stout<BF>(out0, obase + p, camv/den);
    }
}

// ---------------- 10. K matrix (scrambled j' = k*21+c) + zero sync bufs ------
__global__ void k_kmat(const float* __restrict__ D, const float* __restrict__ inv_ot,
                       const float* __restrict__ invc_ot, float* __restrict__ Kg,
                       float* __restrict__ errg, int* __restrict__ arrv){
    if (blockIdx.x == 0){
        for (int i = threadIdx.x; i < NIMG*(SINK_MAX+1); i += 256){ errg[i] = 0.f; arrv[i] = 0; }
    }
    int g = blockIdx.x*256 + threadIdx.x;         // NIMG*NCLS*HW threads
    int n = g / (NCLS*HW);
    int rem = g - n*(NCLS*HW);
    int c = rem >> 12, p = rem & 4095;
    const float* dp = D + ((size_t)n*HW + p)*NJP;
    float io = inv_ot[n*HW + p];
    float s0 = dp[c]      * io * invc_ot[n*NJ + c];       // k2=0 -> j'=c  (flat 2c+k order)
    float s1 = dp[21 + c] * io * invc_ot[n*NJ + 21 + c];  // k2=1 -> j'=21+c
    Kg[(size_t)g*2 + 0] = expf((s0 - 1.f)*10.f);
    Kg[(size_t)g*2 + 1] = expf((s1 - 1.f)*10.f);
}

// ---------------- 11. Sinkhorn (faithful while-loop, joint per-image err) ----
template<int BF>
__global__ __launch_bounds__(256) void k_sink(const float* __restrict__ Kg,
                                              float* __restrict__ errg,
                                              int* __restrict__ arrv,
                                              void* __restrict__ d_out,
                                              const int* __restrict__ dflag){
    if (*dflag != BF) return;
    __shared__ float K0s[HW]; __shared__ float K1s[HW]; __shared__ float rs[HW];
    __shared__ float wred[4][3]; __shared__ float sh[3];
    int b = blockIdx.x; int n = b / NCLS;
    int tid = threadIdx.x, lane = tid & 63, w = tid >> 6;
    const float* Kb = Kg + (size_t)b*HW*2;
    for (int p = tid; p < HW; p += 256){ K0s[p] = Kb[p*2]; K1s[p] = Kb[p*2+1]; rs[p] = 1.f; }
    float cc0 = 1.f, cc1 = 1.f, err = 1e30f;
    const float u = 1.f/4096.f;
    int iter = 0;
    __syncthreads();
    while (iter < SINK_MAX && err >= 0.01f){
        float p0 = 0.f, p1 = 0.f, es = 0.f;
        for (int p = tid; p < HW; p += 256){
            float k0 = K0s[p], k1 = K1s[p];
            float rn = u / (k0*cc0 + k1*cc1);
            es += fabsf(rn - rs[p]);
            rs[p] = rn;
            p0 += k0*rn; p1 += k1*rn;
        }
        #pragma unroll
        for (int off = 32; off; off >>= 1){
            p0 += __shfl_xor(p0, off); p1 += __shfl_xor(p1, off); es += __shfl_xor(es, off);
        }
        if (lane == 0){ wred[w][0] = p0; wred[w][1] = p1; wred[w][2] = es; }
        __syncthreads();
        if (tid == 0){
            float P0 = wred[0][0]+wred[1][0]+wred[2][0]+wred[3][0];
            float P1 = wred[0][1]+wred[1][1]+wred[2][1]+wred[3][1];
            float ES = wred[0][2]+wred[1][2]+wred[2][2]+wred[3][2];
            sh[0] = 0.5f/P0; sh[1] = 0.5f/P1;
            int slot = n*(SINK_MAX+1) + iter;
            atomicAdd(&errg[slot], ES);
            __threadfence();
            atomicAdd(&arrv[slot], 1);
            while (__hip_atomic_load(&arrv[slot], __ATOMIC_ACQUIRE, __HIP_MEMORY_SCOPE_AGENT) < NCLS)
                __builtin_amdgcn_s_sleep(8);
            sh[2] = __hip_atomic_load(&errg[slot], __ATOMIC_RELAXED, __HIP_MEMORY_SCOPE_AGENT)
                    * (1.f/((float)NCLS*HW));
        }
        __syncthreads();
        cc0 = sh[0]; cc1 = sh[1]; err = sh[2];
        iter++;
    }
    // out1 starts at element offset NIMG*NCLS*HW in d_out
    size_t o1 = (size_t)NIMG*NCLS*HW + (size_t)b*NK*HW;   // [n][c][k][hw]
    for (int p = tid; p < HW; p += 256){
        float rv = rs[p];
        stout<BF>(d_out, o1 + p,      rv*cc0*K0s[p]);
        stout<BF>(d_out, o1 + HW + p, rv*cc1*K1s[p]);
    }
}

// ---------------- host -------------------------------------------------------
extern "C" void kernel_launch(void* const* d_in, const int* in_sizes, int n_in,
                              void* d_out, int out_size, void* d_ws, size_t ws_size,
                              hipStream_t stream){
    const void* cam   = d_in[0];
    const void* label = d_in[1];
    const void* feat  = d_in[2];

    char* ws = (char*)d_ws; size_t off = 0;
    auto alloc = [&](size_t bytes)->char*{
        char* p = ws + off; off = (off + bytes + 255) & ~(size_t)255; return p;
    };
    int*    dflag    = (int*)   alloc(4);
    float*  featT    = (float*) alloc((size_t)NIMG*HW*CF*4);   // f32, not bf16!
    double* centers  = (double*)alloc((size_t)NIMG*NCLS*NK*CF*8);
    float*  Cf32     = (float*) alloc((size_t)NIMG*NJP*CF*4);
    float*  inv_n    = (float*) alloc((size_t)NIMG*HW*4);
    float*  inv_ot   = (float*) alloc((size_t)NIMG*HW*4);
    int*    pix_cls  = (int*)   alloc((size_t)NIMG*HW*4);
    int*    cnt      = (int*)   alloc((size_t)NIMG*NCLS*4);
    int*    plist    = (int*)   alloc((size_t)NIMG*NCLS*HW*4);
    float*  invc_cam = (float*) alloc((size_t)NIMG*NJ*4);
    float*  invc_ot  = (float*) alloc((size_t)NIMG*NJ*4);
    float*  D        = (float*) alloc((size_t)NIMG*HW*NJP*4);
    float*  Kg       = (float*) alloc((size_t)NIMG*NCLS*HW*NK*4);
    float*  errg     = (float*) alloc((size_t)NIMG*(SINK_MAX+1)*4);
    int*    arrv     = (int*)   alloc((size_t)NIMG*(SINK_MAX+1)*4);

    k_detect<<<1, 256, 0, stream>>>(feat, dflag);

    k_seeds<1><<<NIMG*HW/256, 256, 0, stream>>>(cam, label, pix_cls, dflag);
    k_seeds<0><<<NIMG*HW/256, 256, 0, stream>>>(cam, label, pix_cls, dflag);
    k_norms<1><<<NIMG*HW/256, 256, 0, stream>>>(feat, inv_n, inv_ot, dflag);
    k_norms<0><<<NIMG*HW/256, 256, 0, stream>>>(feat, inv_n, inv_ot, dflag);
    k_transpose<1><<<NIMG*(CF/64)*(HW/64), 256, 0, stream>>>(feat, featT, dflag);
    k_transpose<0><<<NIMG*(CF/64)*(HW/64), 256, 0, stream>>>(feat, featT, dflag);

    k_scan  <<<NIMG*NCLS, 64, 0, stream>>>(pix_cls, featT, cnt, plist, centers);
    k_kmeans<<<NIMG*NCLS, 512, 0, stream>>>(cnt, plist, featT, centers);
    k_invc  <<<NIMG*NJ, 64, 0, stream>>>(centers, invc_cam, invc_ot);
    k_cf32  <<<NIMG, 256, 0, stream>>>(centers, Cf32);
    k_gemmf <<<NIMG*64, 256, 0, stream>>>(featT, Cf32, D);

    k_out0<1><<<NIMG*NCLS, 256, 0, stream>>>(D, inv_n, invc_cam, cnt, d_out, dflag);
    k_out0<0><<<NIMG*NCLS, 256, 0, stream>>>(D, inv_n, invc_cam, cnt, d_out, dflag);

    k_kmat  <<<NIMG*NCLS*HW/256, 256, 0, stream>>>(D, inv_ot, invc_ot, Kg, errg, arrv);

    k_sink<1><<<NIMG*NCLS, 256, 0, stream>>>(Kg, errg, arrv, d_out, dflag);
    k_sink<0><<<NIMG*NCLS, 256, 0, stream>>>(Kg, errg, arrv, d_out, dflag);
}

// Round 4
// 728.012 us; speedup vs baseline: 1.7226x; 1.7226x over previous
//
#include <hip/hip_runtime.h>
#include <hip/hip_bf16.h>
#include <stdint.h>

#define NIMG 8
#define NCLS 21
#define HW   4096
#define CF   768
#define NK   2
#define NJ   42
#define NJP  48
#define SINK_MAX 100

using uint32 = unsigned int;
using u16    = unsigned short;

__device__ __forceinline__ float b2f(u16 u){ union{uint32 i; float f;} x; x.i=((uint32)u)<<16; return x.f; }
__device__ __forceinline__ u16 f2b(float f){ union{float f; uint32 i;} x; x.f=f; return (u16)((x.i + 0x7fffu + ((x.i>>16)&1u))>>16); }

template<int BF>
__device__ __forceinline__ float ldin(const void* p, size_t idx){
    if (BF) return b2f(((const u16*)p)[idx]);
    return ((const float*)p)[idx];
}
template<int BF>
__device__ __forceinline__ void stout(void* p, size_t idx, float v){
    if (BF) ((u16*)p)[idx] = f2b(v);
    else    ((float*)p)[idx] = v;
}

// ---------------- 0. dtype detect: bf16 (flag=1) vs f32 (flag=0) -------------
__global__ void k_detect(const void* feat, int* flag){
    __shared__ int cnt;
    if (threadIdx.x == 0) cnt = 0;
    __syncthreads();
    const u16* f = (const u16*)feat;
    int bad = 0;
    for (int i = threadIdx.x; i < 4096; i += 256){
        int ex = (f[i] >> 7) & 0xFF;        // bf16 exponent field
        if (ex >= 160) bad++;               // |v| >= 2^33: impossible for N(0,1) bf16
    }
    atomicAdd(&cnt, bad);
    __syncthreads();
    if (threadIdx.x == 0) *flag = (cnt < 64) ? 1 : 0;
}

// ---------------- 1. per-pixel class assignment (argmax CAM, label-gated) ----
template<int BF>
__global__ void k_seeds(const void* __restrict__ cam, const void* __restrict__ label,
                        int* __restrict__ pix_cls, const int* __restrict__ dflag){
    if (*dflag != BF) return;
    int g = blockIdx.x*256 + threadIdx.x;        // NIMG*HW threads
    int n = g >> 12, p = g & 4095;
    float best = -1e30f; int bel = 0;
    for (int c = 0; c < NCLS; c++){
        float v = ldin<BF>(cam, (size_t)(n*NCLS + c)*HW + p);
        if (v > best){ best = v; bel = c; }      // strict > : first-max tie-break
    }
    pix_cls[g] = (ldin<BF>(label, n*NCLS + bel) > 0.f) ? bel : -1;
}

// ---------------- 2. per-pixel feature norms (f64 accumulate) ----------------
template<int BF>
__global__ void k_norms(const void* __restrict__ feat, float* __restrict__ inv_n,
                        float* __restrict__ inv_ot, const int* __restrict__ dflag){
    if (*dflag != BF) return;
    int g = blockIdx.x*256 + threadIdx.x;        // NIMG*HW threads
    int n = g >> 12, p = g & 4095;
    double s = 0.0;
    for (int k = 0; k < CF; k++){
        double v = (double)ldin<BF>(feat, (size_t)(n*CF + k)*HW + p);
        s += v*v;
    }
    double nr = sqrt(s);
    inv_n [g] = (float)(1.0/fmax(nr, 1e-8));
    inv_ot[g] = (float)(1.0/(nr + 1e-5));
}

// ------- 3. transpose feature [cf,hw] -> featT [hw,cf] in FULL f32 -----------
// (round-3 post-mortem: bf16-rounding features here was the stable 0.08 error)
template<int BF>
__global__ void k_transpose(const void* __restrict__ feat, float* __restrict__ featT,
                            const int* __restrict__ dflag){
    if (*dflag != BF) return;
    __shared__ float tile[64][65];
    int b = blockIdx.x;
    int n   = b / ((CF/64)*(HW/64));
    int rem = b % ((CF/64)*(HW/64));
    int kb = (rem / (HW/64)) * 64;
    int pb = (rem % (HW/64)) * 64;
    int tx = threadIdx.x & 63, ty = threadIdx.x >> 6;
    for (int i = 0; i < 16; i++){
        int k = ty*16 + i;
        tile[tx][k] = ldin<BF>(feat, ((size_t)(n*CF + kb + k))*HW + pb + tx);
    }
    __syncthreads();
    for (int i = 0; i < 16; i++){
        int p = ty*16 + i;
        featT[((size_t)(n*HW + pb + p))*CF + kb + tx] = tile[p][tx];
    }
}

// ---------------- 4. per-(n,c): count, ordered pixel list, init centers ------
__global__ void k_scan(const int* __restrict__ pix_cls, const float* __restrict__ featT,
                       int* __restrict__ cnt, int* __restrict__ plist,
                       double* __restrict__ centers){
    int b = blockIdx.x; int n = b / NCLS, c = b % NCLS;
    int lane = threadIdx.x;                       // 64 threads = 1 wave
    int* lst = plist + (size_t)b*HW;
    int count = 0, i0 = -1, i1 = -1;
    for (int base = 0; base < HW; base += 64){
        int cls = pix_cls[n*HW + base + lane];
        unsigned long long m = __ballot(cls == c);
        int pos = count + __popcll(m & ((1ull<<lane) - 1ull));
        if (cls == c) lst[pos] = base + lane;
        if (i0 < 0){
            if (m){ i0 = base + __ffsll((long long)m) - 1;
                    unsigned long long m2 = m & (m-1);
                    if (m2) i1 = base + __ffsll((long long)m2) - 1; }
        } else if (i1 < 0){
            if (m) i1 = base + __ffsll((long long)m) - 1;
        }
        count += __popcll(m);
    }
    if (lane == 0) cnt[b] = count;
    double* C0 = centers + (size_t)b*NK*CF;
    if (count >= 2){
        const float* r0 = featT + (size_t)(n*HW + i0)*CF;
        const float* r1 = featT + (size_t)(n*HW + i1)*CF;
        for (int e = lane; e < CF; e += 64){ C0[e] = (double)r0[e]; C0[CF+e] = (double)r1[e]; }
    } else {
        for (int e = lane; e < CF; e += 64){ C0[e] = 0.0; C0[CF+e] = 0.0; }
    }
}

// -------- 5. k-means (<=10 Lloyd iterations) per (n,c) -----------------------
// round-11 post-mortem: round-2's 16-lane slicing spilled (WRITE_SIZE 242MB:
// >190 VGPR needed under a 128-VGPR launch_bounds cap). Round-1 evidence:
// per-iteration cost invariant to prefetch depth -> not load-latency bound;
// VALUBusy ~5% -> stalled, and the only serial structure left is the per-pixel
// cross-lane f64 reduce + waitcnt chains. This version ELIMINATES cross-lane
// reduction from the hot path:
//   pass A: thread owns a pixel (m<=4096, 512-strided), streams its row with
//           float4, f64 dots via 8 independent FMA chains, centers broadcast
//           from LDS (wave-uniform addr, conflict-free). No shuffles/atomics.
//   pass B: thread owns 1-2 center ELEMENTS (768=512+256), streams pixel rows
//           coalesced, masked accumulate in registers. One owner per element
//           -> zero reduction. Counts: one int butterfly per wave per iter.
// f64 dots (same decisions), f32 sums -> f64 divide (same as passing kernels),
// exact early-exit unchanged. VGPR ~80 by construction; (512,1) = 256 budget.
__global__ __launch_bounds__(512, 1) void k_kmeans(const int* __restrict__ cnt,
                                                   const int* __restrict__ plist,
                                                   const float* __restrict__ featT,
                                                   double* __restrict__ centers){
    int b = blockIdx.x; int n = b / NCLS;
    int m = cnt[b];
    if (m < 2) return;                            // centers stay zero (k_scan wrote them)
    __shared__ double Cs[2][CF];                  // 12 KB canonical centers
    __shared__ double red[2];
    __shared__ double invn[2];
    __shared__ unsigned char asg[HW];             // 4 KB previous assignment
    __shared__ int    lst_s[HW];                  // 16 KB pixel list
    __shared__ int chg;
    __shared__ int ck0i;
    int tid = threadIdx.x, lane = tid & 63;
    const int* lst = plist + (size_t)b*HW;
    double* Cg = centers + (size_t)b*NK*CF;
    const float* fbase = featT + (size_t)n*HW*CF;
    for (int j = tid; j < CF; j += 512){ Cs[0][j] = Cg[j]; Cs[1][j] = Cg[CF+j]; }
    for (int i = tid; i < m; i += 512){ asg[i] = 255; lst_s[i] = lst[i]; }
    __syncthreads();

    for (int it = 0; it < 10; it++){
        if (tid < 2) red[tid] = 0.0;
        if (tid == 0){ chg = 0; ck0i = 0; }
        __syncthreads();
        // center norms (cold path, once per iter)
        double q0 = 0.0, q1 = 0.0;
        for (int j = tid; j < CF; j += 512){ q0 += Cs[0][j]*Cs[0][j]; q1 += Cs[1][j]*Cs[1][j]; }
        #pragma unroll
        for (int off = 32; off; off >>= 1){ q0 += __shfl_xor(q0, off); q1 += __shfl_xor(q1, off); }
        if (lane == 0){ atomicAdd(&red[0], q0); atomicAdd(&red[1], q1); }
        __syncthreads();
        if (tid == 0){
            invn[0] = 1.0/fmax(sqrt(red[0]), 1e-8);
            invn[1] = 1.0/fmax(sqrt(red[1]), 1e-8);
        }
        __syncthreads();
        double ic0 = invn[0], ic1 = invn[1];

        // ---- pass A: per-thread pixel assignment (no cross-lane ops) ----
        int myC0 = 0, myChg = 0;
        for (int l = tid; l < m; l += 512){
            const float* row = fbase + (size_t)lst_s[l]*CF;
            double s0a=0.0,s0b=0.0,s0c=0.0,s0d=0.0;
            double s1a=0.0,s1b=0.0,s1c=0.0,s1d=0.0;
            #pragma unroll 8
            for (int k = 0; k < CF; k += 4){
                float4 f = *(const float4*)(row + k);
                const double* c0 = &Cs[0][k];
                const double* c1 = &Cs[1][k];
                s0a += (double)f.x*c0[0]; s0b += (double)f.y*c0[1];
                s0c += (double)f.z*c0[2]; s0d += (double)f.w*c0[3];
                s1a += (double)f.x*c1[0]; s1b += (double)f.y*c1[1];
                s1c += (double)f.z*c1[2]; s1d += (double)f.w*c1[3];
            }
            double d0 = (s0a+s0b)+(s0c+s0d);
            double d1 = (s1a+s1b)+(s1c+s1d);
            int a = (d0*ic0 >= d1*ic1) ? 0 : 1;   // argmax, first-max on tie
            if (a == 0) myC0++;
            if (asg[l] != (unsigned char)a){ myChg++; asg[l] = (unsigned char)a; }
        }
        // block reduce of counts (once per iter): int butterfly + lane0 atomic
        #pragma unroll
        for (int off = 32; off; off >>= 1){
            myC0  += __shfl_xor(myC0,  off);
            myChg += __shfl_xor(myChg, off);
        }
        if (lane == 0){
            if (myC0)  atomicAdd(&ck0i, myC0);
            if (myChg) atomicAdd(&chg,  myChg);
        }
        __syncthreads();
        if (chg == 0) break;                      // exact fixed point: Cs already final
        int c0tot = ck0i;
        double dv0 = fmax((double)c0tot, 1.0);
        double dv1 = fmax((double)(m - c0tot), 1.0);

        // ---- pass B: per-thread-element center sums (no reduction needed) ----
        float a00 = 0.f, a01 = 0.f, a10 = 0.f, a11 = 0.f;
        #pragma unroll 4
        for (int p = 0; p < m; p++){
            const float* r = fbase + (size_t)lst_s[p]*CF;
            int aa = asg[p];
            float v0 = r[tid];
            float v1 = (tid < 256) ? r[512 + tid] : 0.f;
            if (aa == 0){ a00 += v0; a01 += v1; }
            else        { a10 += v0; a11 += v1; }
        }
        Cs[0][tid] = (double)a00/dv0;
        Cs[1][tid] = (double)a10/dv1;
        if (tid < 256){
            Cs[0][512 + tid] = (double)a01/dv0;
            Cs[1][512 + tid] = (double)a11/dv1;
        }
        __syncthreads();
    }
    for (int j = tid; j < CF; j += 512){ Cg[j] = Cs[0][j]; Cg[CF+j] = Cs[1][j]; }
}

// ---------------- 6. inverse center norms (f64, both epsilon variants) -------
__global__ void k_invc(const double* __restrict__ centers, float* __restrict__ invc_cam,
                       float* __restrict__ invc_ot){
    int b = blockIdx.x;                           // NIMG*NJ blocks, 64 threads
    int lane = threadIdx.x;
    const double* C = centers + (size_t)b*CF;
    double s = 0.0;
    for (int e = lane; e < CF; e += 64) s += C[e]*C[e];
    for (int off = 32; off; off >>= 1) s += __shfl_xor(s, off);
    if (lane == 0){
        double nr = sqrt(s);
        invc_cam[b] = (float)(1.0/fmax(nr, 1e-8));
        invc_ot[b]  = (float)(1.0/(nr + 1e-5));
    }
}

// ---------------- 7. centers f64 -> f32 padded [48,768] ----------------------
__global__ void k_cf32(const double* __restrict__ centers, float* __restrict__ Cf32){
    int n = blockIdx.x; int tid = threadIdx.x;
    for (int idx = tid; idx < NJP*CF; idx += 256){
        int j = idx / CF, e = idx - j*CF;
        float v = (j < NJ) ? (float)centers[((size_t)n*NJ + j)*CF + e] : 0.f;
        Cf32[(size_t)n*NJP*CF + idx] = v;
    }
}

// ---------------- 8. big sim GEMM in f32: D[p][j] = feat[p]·C[j] -------------
__global__ __launch_bounds__(256) void k_gemmf(const float* __restrict__ featT,
                                               const float* __restrict__ Cf32,
                                               float* __restrict__ D){
    __shared__ float Fs[128][66];                 // [k][p], padded
    int b = blockIdx.x; int n = b >> 6; int pbase = (b & 63)*64;
    int tid = threadIdx.x, p = tid & 63;
    int jb = __builtin_amdgcn_readfirstlane((tid >> 6)*12);   // wave-uniform j-base
    float acc[12];
    #pragma unroll
    for (int j = 0; j < 12; j++) acc[j] = 0.f;
    for (int kc = 0; kc < CF; kc += 128){
        __syncthreads();
        for (int idx = tid; idx < 64*64; idx += 256){         // 64 px × 64 float2
            int pp = idx >> 6, cw = idx & 63;
            float2 wv = *(const float2*)(featT + (size_t)(n*HW + pbase + pp)*CF + kc + cw*2);
            Fs[cw*2    ][pp] = wv.x;
            Fs[cw*2 + 1][pp] = wv.y;
        }
        __syncthreads();
        const float* Cb = Cf32 + (size_t)n*NJP*CF + kc;
        for (int k8 = 0; k8 < 128; k8 += 8){
            #pragma unroll
            for (int j = 0; j < 12; j++){
                const float* cr = Cb + (size_t)(jb + j)*CF + k8;
                #pragma unroll
                for (int k = 0; k < 8; k++)
                    acc[j] += Fs[k8 + k][p] * cr[k];
            }
        }
    }
    float* dp = D + ((size_t)(n*HW + pbase + p))*NJP + jb;
    #pragma unroll
    for (int j = 0; j < 12; j++) dp[j] = acc[j];
}

// ---------------- 9. output 0: cam, max-normalized ---------------------------
template<int BF>
__global__ __launch_bounds__(256) void k_out0(const float* __restrict__ D,
                                              const float* __restrict__ inv_n,
                                              const float* __restrict__ invc_cam,
                                              const int* __restrict__ cnt,
                                              void* __restrict__ out0,
                                              const int* __restrict__ dflag){
    if (*dflag != BF) return;
    int b = blockIdx.x; int n = b / NCLS, c = b % NCLS;
    __shared__ float wmax[4]; __shared__ float sden;
    int tid = threadIdx.x, lane = tid & 63, w = tid >> 6;
    size_t obase = (size_t)b*HW;
    if (cnt[b] < 2){
        for (int p = tid; p < HW; p += 256) stout<BF>(out0, obase + p, 0.f);
        return;
    }
    float ic0 = invc_cam[n*NJ + 2*c], ic1 = invc_cam[n*NJ + 2*c + 1];
    const float* Dn = D + (size_t)n*HW*NJP;
    float mx = -1e30f;
    for (int p = tid; p < HW; p += 256){
        const float* dp = Dn + (size_t)p*NJP + 2*c;
        float camv = 0.5f*(dp[0]*ic0 + dp[1]*ic1)*inv_n[n*HW + p];
        mx = fmaxf(mx, camv);
    }
    for (int off = 32; off; off >>= 1) mx = fmaxf(mx, __shfl_xor(mx, off));
    if (lane == 0) wmax[w] = mx;
    __syncthreads();
    if (tid == 0) sden = fmaxf(fmaxf(wmax[0], wmax[1]), fmaxf(wmax[2], wmax[3])) + 1e-5f;
    __syncthreads();
    float den = sden;
    for (int p = tid; p < HW; p += 256){
        const float* dp = Dn + (size_t)p*NJP + 2*c;
        float camv = 0.5f*(dp[0]*ic0 + dp[1]*ic1)*inv_n[n*HW + p];
        stout<BF>(out0, obase + p, camv/den);
    }
}

// ---------------- 10. K matrix (scrambled j' = k*21+c) + zero sync bufs ------
__global__ void k_kmat(const float* __restrict__ D, const float* __restrict__ inv_ot,
                       const float* __restrict__ invc_ot, float* __restrict__ Kg,
                       float* __restrict__ errg, int* __restrict__ arrv){
    if (blockIdx.x == 0){
        for (int i = threadIdx.x; i < NIMG*(SINK_MAX+1); i += 256){ errg[i] = 0.f; arrv[i] = 0; }
    }
    int g = blockIdx.x*256 + threadIdx.x;         // NIMG*NCLS*HW threads
    int n = g / (NCLS*HW);
    int rem = g - n*(NCLS*HW);
    int c = rem >> 12, p = rem & 4095;
    const float* dp = D + ((size_t)n*HW + p)*NJP;
    float io = inv_ot[n*HW + p];
    float s0 = dp[c]      * io * invc_ot[n*NJ + c];       // k2=0 -> j'=c  (flat 2c+k order)
    float s1 = dp[21 + c] * io * invc_ot[n*NJ + 21 + c];  // k2=1 -> j'=21+c
    Kg[(size_t)g*2 + 0] = expf((s0 - 1.f)*10.f);
    Kg[(size_t)g*2 + 1] = expf((s1 - 1.f)*10.f);
}

// ---------------- 11. Sinkhorn (faithful while-loop, joint per-image err) ----
template<int BF>
__global__ __launch_bounds__(256) void k_sink(const float* __restrict__ Kg,
                                              float* __restrict__ errg,
                                              int* __restrict__ arrv,
                                              void* __restrict__ d_out,
                                              const int* __restrict__ dflag){
    if (*dflag != BF) return;
    __shared__ float K0s[HW]; __shared__ float K1s[HW]; __shared__ float rs[HW];
    __shared__ float wred[4][3]; __shared__ float sh[3];
    int b = blockIdx.x; int n = b / NCLS;
    int tid = threadIdx.x, lane = tid & 63, w = tid >> 6;
    const float* Kb = Kg + (size_t)b*HW*2;
    for (int p = tid; p < HW; p += 256){ K0s[p] = Kb[p*2]; K1s[p] = Kb[p*2+1]; rs[p] = 1.f; }
    float cc0 = 1.f, cc1 = 1.f, err = 1e30f;
    const float u = 1.f/4096.f;
    int iter = 0;
    __syncthreads();
    while (iter < SINK_MAX && err >= 0.01f){
        float p0 = 0.f, p1 = 0.f, es = 0.f;
        for (int p = tid; p < HW; p += 256){
            float k0 = K0s[p], k1 = K1s[p];
            float rn = u / (k0*cc0 + k1*cc1);
            es += fabsf(rn - rs[p]);
            rs[p] = rn;
            p0 += k0*rn; p1 += k1*rn;
        }
        #pragma unroll
        for (int off = 32; off; off >>= 1){
            p0 += __shfl_xor(p0, off); p1 += __shfl_xor(p1, off); es += __shfl_xor(es, off);
        }
        if (lane == 0){ wred[w][0] = p0; wred[w][1] = p1; wred[w][2] = es; }
        __syncthreads();
        if (tid == 0){
            float P0 = wred[0][0]+wred[1][0]+wred[2][0]+wred[3][0];
            float P1 = wred[0][1]+wred[1][1]+wred[2][1]+wred[3][1];
            float ES = wred[0][2]+wred[1][2]+wred[2][2]+wred[3][2];
            sh[0] = 0.5f/P0; sh[1] = 0.5f/P1;
            int slot = n*(SINK_MAX+1) + iter;
            atomicAdd(&errg[slot], ES);
            __threadfence();
            atomicAdd(&arrv[slot], 1);
            while (__hip_atomic_load(&arrv[slot], __ATOMIC_ACQUIRE, __HIP_MEMORY_SCOPE_AGENT) < NCLS)
                __builtin_amdgcn_s_sleep(8);
            sh[2] = __hip_atomic_load(&errg[slot], __ATOMIC_RELAXED, __HIP_MEMORY_SCOPE_AGENT)
                    * (1.f/((float)NCLS*HW));
        }
        __syncthreads();
        cc0 = sh[0]; cc1 = sh[1]; err = sh[2];
        iter++;
    }
    // out1 starts at element offset NIMG*NCLS*HW in d_out
    size_t o1 = (size_t)NIMG*NCLS*HW + (size_t)b*NK*HW;   // [n][c][k][hw]
    for (int p = tid; p < HW; p += 256){
        float rv = rs[p];
        stout<BF>(d_out, o1 + p,      rv*cc0*K0s[p]);
        stout<BF>(d_out, o1 + HW + p, rv*cc1*K1s[p]);
    }
}

// ---------------- host -------------------------------------------------------
extern "C" void kernel_launch(void* const* d_in, const int* in_sizes, int n_in,
                              void* d_out, int out_size, void* d_ws, size_t ws_size,
                              hipStream_t stream){
    const void* cam   = d_in[0];
    const void* label = d_in[1];
    const void* feat  = d_in[2];

    char* ws = (char*)d_ws; size_t off = 0;
    auto alloc = [&](size_t bytes)->char*{
        char* p = ws + off; off = (off + bytes + 255) & ~(size_t)255; return p;
    };
    int*    dflag    = (int*)   alloc(4);
    float*  featT    = (float*) alloc((size_t)NIMG*HW*CF*4);   // f32, not bf16!
    double* centers  = (double*)alloc((size_t)NIMG*NCLS*NK*CF*8);
    float*  Cf32     = (float*) alloc((size_t)NIMG*NJP*CF*4);
    float*  inv_n    = (float*) alloc((size_t)NIMG*HW*4);
    float*  inv_ot   = (float*) alloc((size_t)NIMG*HW*4);
    int*    pix_cls  = (int*)   alloc((size_t)NIMG*HW*4);
    int*    cnt      = (int*)   alloc((size_t)NIMG*NCLS*4);
    int*    plist    = (int*)   alloc((size_t)NIMG*NCLS*HW*4);
    float*  invc_cam = (float*) alloc((size_t)NIMG*NJ*4);
    float*  invc_ot  = (float*) alloc((size_t)NIMG*NJ*4);
    float*  D        = (float*) alloc((size_t)NIMG*HW*NJP*4);
    float*  Kg       = (float*) alloc((size_t)NIMG*NCLS*HW*NK*4);
    float*  errg     = (float*) alloc((size_t)NIMG*(SINK_MAX+1)*4);
    int*    arrv     = (int*)   alloc((size_t)NIMG*(SINK_MAX+1)*4);

    k_detect<<<1, 256, 0, stream>>>(feat, dflag);

    k_seeds<1><<<NIMG*HW/256, 256, 0, stream>>>(cam, label, pix_cls, dflag);
    k_seeds<0><<<NIMG*HW/256, 256, 0, stream>>>(cam, label, pix_cls, dflag);
    k_norms<1><<<NIMG*HW/256, 256, 0, stream>>>(feat, inv_n, inv_ot, dflag);
    k_norms<0><<<NIMG*HW/256, 256, 0, stream>>>(feat, inv_n, inv_ot, dflag);
    k_transpose<1><<<NIMG*(CF/64)*(HW/64), 256, 0, stream>>>(feat, featT, dflag);
    k_transpose<0><<<NIMG*(CF/64)*(HW/64), 256, 0, stream>>>(feat, featT, dflag);

    k_scan  <<<NIMG*NCLS, 64, 0, stream>>>(pix_cls, featT, cnt, plist, centers);
    k_kmeans<<<NIMG*NCLS, 512, 0, stream>>>(cnt, plist, featT, centers);
    k_invc  <<<NIMG*NJ, 64, 0, stream>>>(centers, invc_cam, invc_ot);
    k_cf32  <<<NIMG, 256, 0, stream>>>(centers, Cf32);
    k_gemmf <<<NIMG*64, 256, 0, stream>>>(featT, Cf32, D);

    k_out0<1><<<NIMG*NCLS, 256, 0, stream>>>(D, inv_n, invc_cam, cnt, d_out, dflag);
    k_out0<0><<<NIMG*NCLS, 256, 0, stream>>>(D, inv_n, invc_cam, cnt, d_out, dflag);

    k_kmat  <<<NIMG*NCLS*HW/256, 256, 0, stream>>>(D, inv_ot, invc_ot, Kg, errg, arrv);

    k_sink<1><<<NIMG*NCLS, 256, 0, stream>>>(Kg, errg, arrv, d_out, dflag);
    k_sink<0><<<NIMG*NCLS, 256, 0, stream>>>(Kg, errg, arrv, d_out, dflag);
}